// Round 5
// baseline (21510.410 us; speedup 1.0000x reference)
//
#include <hip/hip_runtime.h>

typedef unsigned short ushort_t;
typedef unsigned int uint_t;
typedef unsigned long long ull_t;
typedef __attribute__((ext_vector_type(8))) short short8;
typedef __attribute__((ext_vector_type(4))) float f32x4;
typedef __attribute__((ext_vector_type(4))) uint_t uint4v;

// ---------------- workspace layout (bytes) ----------------
constexpr size_t OFF_WSFT = 0;                               // bf16 [512][512]  WsfT[n][k]=W_sf[k][n]
constexpr size_t OFF_WAFT = OFF_WSFT + 512*512*2;            // bf16 [512][512]
constexpr size_t OFF_WAST = OFF_WAFT + 512*512*2;            // bf16 [512][1024]
constexpr size_t OFF_WSST = OFF_WAST + 512*1024*2;           // bf16 [512][1024]
constexpr size_t OFF_WO1T = OFF_WSST + 512*1024*2;           // bf16 [512][1536]
constexpr size_t OFF_XTAB = OFF_WO1T + 512*1536*2;           // bf16 [600][512]
constexpr size_t OFF_PRO  = OFF_XTAB + 600*512*2;            // bf16 [300][512]
constexpr size_t OFF_GAP  = OFF_PRO  + 300*512*2;            // f32  [200][512]
constexpr size_t OFF_CAF  = OFF_GAP  + 200*512*4;            // f32  [512]
constexpr size_t OFF_LAG  = OFF_CAF  + 512*4;                // bf16 [512][512] gated last_all (exchange)
constexpr size_t OFF_LSG  = OFF_LAG  + 512*512*2;            // bf16 [512][512] gated last_sk
constexpr size_t OFF_ASG  = OFF_LSG  + 512*512*2;            // bf16 [512][512] all_state
constexpr size_t OFF_BAR  = OFF_ASG  + 512*512*2;            // i32  [8 sets][64]: c1@0 c2@16 d1@32 d2@48
constexpr size_t OFF_SKB  = OFF_BAR  + 8*64*4;               // bf16 [512][199][512] skill_buf
constexpr size_t WS_NEED  = OFF_SKB  + (size_t)512*199*512*2;

__device__ __forceinline__ ushort_t f2bf(float f) {
  union { float f; uint_t u; } v; v.f = f;
  uint_t u = v.u;
  return (ushort_t)((u + 0x7FFFu + ((u >> 16) & 1u)) >> 16);
}
__device__ __forceinline__ float bf2f(ushort_t h) {
  union { uint_t u; float f; } v; v.u = ((uint_t)h) << 16;
  return v.f;
}

__device__ __forceinline__ ull_t coh_ld8(const void* p) {
  return __hip_atomic_load((const ull_t*)p, __ATOMIC_RELAXED, __HIP_MEMORY_SCOPE_AGENT);
}
__device__ __forceinline__ void coh_st8(void* p, ull_t v) {
  __hip_atomic_store((ull_t*)p, v, __ATOMIC_RELAXED, __HIP_MEMORY_SCOPE_AGENT);
}

// ---------------- prologue ----------------
__global__ void rekt_prep(const float* __restrict__ skill_embed, const float* __restrict__ ans_embed,
                          const float* __restrict__ ls_state, const float* __restrict__ skill_state0,
                          const float* __restrict__ W_sf, const float* __restrict__ W_af,
                          const float* __restrict__ W_ss, const float* __restrict__ W_as,
                          const float* __restrict__ W_o1,
                          float* __restrict__ d_out, char* __restrict__ ws) {
  ushort_t* WsfT = (ushort_t*)(ws + OFF_WSFT);
  ushort_t* WafT = (ushort_t*)(ws + OFF_WAFT);
  ushort_t* WasT = (ushort_t*)(ws + OFF_WAST);
  ushort_t* WssT = (ushort_t*)(ws + OFF_WSST);
  ushort_t* Wo1T = (ushort_t*)(ws + OFF_WO1T);
  ushort_t* Xtab = (ushort_t*)(ws + OFF_XTAB);
  ushort_t* PROt = (ushort_t*)(ws + OFF_PRO);
  ushort_t* ASG  = (ushort_t*)(ws + OFF_ASG);
  int*      BARp = (int*)(ws + OFF_BAR);
  ushort_t* SKB  = (ushort_t*)(ws + OFF_SKB);

  const size_t t0 = (size_t)blockIdx.x * blockDim.x + threadIdx.x;
  const size_t st = (size_t)gridDim.x * blockDim.x;

  for (size_t i = t0; i < 512*512; i += st) {
    int k = (int)(i >> 9), n = (int)(i & 511);
    WsfT[(size_t)n*512 + k] = f2bf(W_sf[i]);
    WafT[(size_t)n*512 + k] = f2bf(W_af[i]);
  }
  for (size_t i = t0; i < 1024*512; i += st) {
    int k = (int)(i >> 9), n = (int)(i & 511);
    WasT[(size_t)n*1024 + k] = f2bf(W_as[i]);
    WssT[(size_t)n*1024 + k] = f2bf(W_ss[i]);
  }
  for (size_t i = t0; i < 1536*512; i += st) {
    int k = (int)(i >> 9), n = (int)(i & 511);
    Wo1T[(size_t)n*1536 + k] = f2bf(W_o1[i]);
  }
  for (size_t i = t0; i < 600*512; i += st) {
    int row = (int)(i >> 9), jj = (int)(i & 511);
    int a = row / 300, sk = row % 300;
    Xtab[i] = f2bf(skill_embed[(size_t)sk*512 + jj] + ans_embed[(size_t)a*512 + jj]);
  }
  for (size_t i = t0; i < 300*512; i += st) PROt[i] = f2bf(skill_embed[i]);
  for (size_t i = t0; i < 512*512; i += st) ASG[i] = f2bf(ls_state[i & 511]);
  for (size_t i = t0; i < 512*512; i += st) {
    size_t b = i >> 9, n = i & 511;
    SKB[((size_t)b*199)*512 + n] = f2bf(skill_state0[n]);
  }
  for (size_t i = t0; i < 512*199; i += st) d_out[i] = 0.f;
  for (size_t i = t0; i < 8*64; i += st) BARp[i] = 0;
}

// GAP / CAF precompute
__global__ void rekt_gap(const float* __restrict__ time_embed,
                         const float* __restrict__ W_sf, const float* __restrict__ b_sf,
                         const float* __restrict__ W_af, const float* __restrict__ b_af,
                         char* __restrict__ ws) {
  float* GAP = (float*)(ws + OFF_GAP);
  float* CAF = (float*)(ws + OFF_CAF);
  const int n = threadIdx.x;
  __shared__ float te[512];
  if (blockIdx.x < 200) {
    const int t = blockIdx.x;
    te[n] = time_embed[(size_t)t*512 + n];
    __syncthreads();
    float acc = b_sf[n];
    for (int k = 0; k < 512; ++k) acc = fmaf(te[k], W_sf[(size_t)(512 + k)*512 + n], acc);
    GAP[(size_t)t*512 + n] = acc;
  } else {
    te[n] = time_embed[512 + n];
    __syncthreads();
    float acc = b_af[n];
    for (int k = 0; k < 512; ++k) acc = fmaf(te[k], W_af[(size_t)(512 + k)*512 + n], acc);
    CAF[n] = acc;
  }
}

// ---------------- split barrier (8 blocks per set), fence-free ----------------
__device__ __forceinline__ void bar_signal(int* cnt) {
  __syncthreads();                               // drains each wave's vm stores
  if (threadIdx.x == 0)
    __hip_atomic_fetch_add(cnt, 1, __ATOMIC_RELAXED, __HIP_MEMORY_SCOPE_AGENT);
}
__device__ __forceinline__ void bar_wait(int* cnt, int target) {
  if (threadIdx.x == 0) {
    while (__hip_atomic_load(cnt, __ATOMIC_RELAXED, __HIP_MEMORY_SCOPE_AGENT) < target)
      __builtin_amdgcn_s_sleep(1);
  }
  __syncthreads();
}

// ---------------- staging helpers ----------------
// coherent: 32 rows x 1KB into swizzled tile (granule gi at gi^(r&7))
__device__ __forceinline__ void stage_coh_gather(short* T, const ushort_t* base, const int* rows, int tid) {
  for (int i = tid; i < 4096; i += 512) {
    const int r = i >> 7, u = i & 127;
    const ull_t v = coh_ld8((const ull_t*)(base + (size_t)rows[r] * 512) + u);
    *reinterpret_cast<ull_t*>(T + r * 512 + ((((u >> 1) ^ (r & 7)) << 3) | ((u & 1) << 2))) = v;
  }
}
__device__ __forceinline__ void stage_coh_linear(short* T, const ushort_t* base, int tid) {
  for (int i = tid; i < 4096; i += 512) {
    const int r = i >> 7, u = i & 127;
    const ull_t v = coh_ld8((const ull_t*)(base + (size_t)r * 512) + u);
    *reinterpret_cast<ull_t*>(T + r * 512 + ((((u >> 1) ^ (r & 7)) << 3) | ((u & 1) << 2))) = v;
  }
}
__device__ __forceinline__ void stage_cached(short* T, const ushort_t* base, const int* rows, int tid) {
  for (int i = tid; i < 2048; i += 512) {
    const int r = i >> 6, gi = i & 63;
    *reinterpret_cast<uint4v*>(T + r * 512 + ((gi ^ (r & 7)) << 3)) =
        *reinterpret_cast<const uint4v*>(base + (size_t)rows[r] * 512 + gi * 8);
  }
}

// ---------------- main scan ----------------
// grid = 64 blocks: block = set ss (8 sets x 64 batches) x slice j (64 cols, XCD j).
// Each block runs TWO 32-row groups interleaved to hide exchange latency.
__global__ __launch_bounds__(512, 1) void rekt_main(
    const int* __restrict__ next_skill, const int* __restrict__ next_ans,
    const float* __restrict__ ls_state,
    const float* __restrict__ b_o1, const float* __restrict__ w_o2,
    const float* __restrict__ b_as, const float* __restrict__ b_ss,
    float* __restrict__ d_out, char* __restrict__ ws) {

  const ushort_t* WsfT = (const ushort_t*)(ws + OFF_WSFT);
  const ushort_t* WafT = (const ushort_t*)(ws + OFF_WAFT);
  const ushort_t* WasT = (const ushort_t*)(ws + OFF_WAST);
  const ushort_t* WssT = (const ushort_t*)(ws + OFF_WSST);
  const ushort_t* Wo1T = (const ushort_t*)(ws + OFF_WO1T);
  const ushort_t* Xtab = (const ushort_t*)(ws + OFF_XTAB);
  const ushort_t* PROt = (const ushort_t*)(ws + OFF_PRO);
  const float*    GAP  = (const float*)(ws + OFF_GAP);
  const float*    CAF  = (const float*)(ws + OFF_CAF);
  ushort_t* LAG = (ushort_t*)(ws + OFF_LAG);
  ushort_t* LSG = (ushort_t*)(ws + OFF_LSG);
  ushort_t* ASG = (ushort_t*)(ws + OFF_ASG);
  int*      BARp = (int*)(ws + OFF_BAR);
  ushort_t* SKB = (ushort_t*)(ws + OFF_SKB);

  __shared__ __align__(16) short T0[32*512];
  __shared__ __align__(16) short T1[32*512];
  __shared__ __align__(16) short T2[32*512];
  __shared__ __align__(16) short T3[32*512];
  __shared__ unsigned char LT[64*300];
  __shared__ int sk_s[64], gap_s[64], xr_s[64], skrow_s[64];
  __shared__ float P_lds[32];

  const int tid = threadIdx.x;
  const int lane = tid & 63, w = tid >> 6;
  const int cc = lane & 15, hi = lane >> 4;
  const int mh = w >> 2, nt = w & 3;
  const int ss = blockIdx.x >> 3, j = blockIdx.x & 7;
  const int bset = ss << 6;                     // 64 batches per set
  const int ncol = j * 64 + nt * 16 + cc;
  const int arow = mh * 16 + cc;
  const int r0 = mh * 16 + (hi << 2);
  int* cbase = BARp + ss * 64;
  int* Cc[2] = {cbase + 0,  cbase + 16};
  int* Cd[2] = {cbase + 32, cbase + 48};

  const float bo1 = b_o1[ncol];
  const float wo2 = w_o2[ncol];
  const float caf = CAF[ncol];
  const float bas = b_as[ncol];
  const float bss = b_ss[ncol];
  const int aswz = (cc & 7) << 3;

  const ushort_t* bsf = WsfT + (size_t)ncol * 512 + hi * 8;
  const ushort_t* baf = WafT + (size_t)ncol * 512 + hi * 8;
  const ushort_t* wo1 = Wo1T + (size_t)ncol * 1536 + hi * 8;
  const ushort_t* was = WasT + (size_t)ncol * 1024 + hi * 8;
  const ushort_t* wss = WssT + (size_t)ncol * 1024 + hi * 8;

  f32x4 as[2], la[2], ls[2];
  {
    const float v = ls_state[ncol];
    as[0] = (f32x4){v, v, v, v};
    as[1] = as[0];
  }

  for (int i = tid; i < 64 * 300; i += 512) LT[i] = 0;
  __syncthreads();

  for (int s = 0; s < 199; ++s) {
    // ================= PHASE A (both groups) =================
#pragma unroll
    for (int gg = 0; gg < 2; ++gg) {
      const int goff = gg << 5;
      bar_wait(Cd[gg], 8 * s);                  // AS/SKB(g) from step s-1 visible
      if (tid < 32) {
        const int lrow = goff + tid;
        const int b = bset + lrow;
        const int sk = next_skill[b * 199 + s];
        const int tl = (int)LT[lrow * 300 + sk];
        sk_s[lrow] = sk;
        gap_s[lrow] = s - tl;
        xr_s[lrow] = next_ans[b * 199 + s] * 300 + sk;
        skrow_s[lrow] = b * 199 + tl;
        LT[lrow * 300 + sk] = (unsigned char)s;
      }
      __syncthreads();
      stage_coh_gather(T0, SKB, skrow_s + goff, tid);
      stage_coh_linear(T1, ASG + (size_t)(bset + goff) * 512, tid);
      if (gg == 0) {                            // g1's X/PRO staged early (T2/T3 idle in A)
        stage_cached(T2, Xtab, xr_s, tid);
        stage_cached(T3, PROt, sk_s, tid);
      }
      __syncthreads();

      f32x4 fa = {0.f,0.f,0.f,0.f}, ga = {0.f,0.f,0.f,0.f};
      {
        const short* a0 = T0 + arow * 512;
        const short* a1 = T1 + arow * 512;
#pragma unroll 4
        for (int kk = 0; kk < 512; kk += 32) {
          const int go = ((((kk >> 3) + hi) << 3) ^ aswz);
          const short8 x0 = *reinterpret_cast<const short8*>(a0 + go);
          const short8 x1 = *reinterpret_cast<const short8*>(a1 + go);
          fa = __builtin_amdgcn_mfma_f32_16x16x32_bf16(x0, *reinterpret_cast<const short8*>(bsf + kk), fa, 0,0,0);
          ga = __builtin_amdgcn_mfma_f32_16x16x32_bf16(x1, *reinterpret_cast<const short8*>(baf + kk), ga, 0,0,0);
        }
      }

      uint_t pa[4], ps[4];
#pragma unroll
      for (int q = 0; q < 4; ++q) {
        const int r = r0 + q;
        const float F = fa[q] + GAP[(size_t)gap_s[goff + r] * 512 + ncol];
        const float sgF = 1.f / (1.f + __expf(-F));
        const float skg = bf2f((ushort_t)T0[r * 512 + (((ncol >> 3) ^ (r & 7)) << 3) + (ncol & 7)]);
        const float lsv = skg * sgF;
        ls[gg][q] = lsv;
        ps[q] = f2bf(lsv);
        const float G = ga[q] + caf;
        const float lav = as[gg][q] * (1.f / (1.f + __expf(-G)));
        la[gg][q] = lav;
        pa[q] = f2bf(lav);
      }
#pragma unroll
      for (int q = 0; q < 4; ++q) {
        const uint_t va = pa[q] | (((uint_t)__shfl_xor((int)pa[q], 1, 64)) << 16);
        const uint_t vs = ps[q] | (((uint_t)__shfl_xor((int)ps[q], 1, 64)) << 16);
        const ull_t wa = (ull_t)va | ((ull_t)(uint_t)__shfl_xor((int)va, 2, 64) << 32);
        const ull_t wv = (ull_t)vs | ((ull_t)(uint_t)__shfl_xor((int)vs, 2, 64) << 32);
        if ((cc & 3) == 0) {
          const size_t row = (size_t)(bset + goff + r0 + q);
          coh_st8(LAG + row * 512 + ncol, wa);
          coh_st8(LSG + row * 512 + ncol, wv);
        }
      }
      bar_signal(Cc[gg]);
    }

    // ================= PHASE B (both groups) =================
#pragma unroll
    for (int gg = 0; gg < 2; ++gg) {
      const int goff = gg << 5;
      bar_wait(Cc[gg], 8 * (s + 1));            // LA/LS(g) visible
      if (tid < 32) P_lds[tid] = 0.f;
      stage_coh_linear(T0, LAG + (size_t)(bset + goff) * 512, tid);
      stage_coh_linear(T1, LSG + (size_t)(bset + goff) * 512, tid);
      if (gg == 1) {
        stage_cached(T2, Xtab, xr_s + 32, tid);
        stage_cached(T3, PROt, sk_s + 32, tid);
      }
      __syncthreads();

      f32x4 h0 = {0.f,0.f,0.f,0.f}, h1 = h0, h2 = h0, na0 = h0, na1 = h0, ns0 = h0, ns1 = h0;
      {
        const short* aLA = T0 + arow * 512;
        const short* aLS = T1 + arow * 512;
        const short* aX  = T2 + arow * 512;
        const short* aP  = T3 + arow * 512;
#pragma unroll 2
        for (int kk = 0; kk < 512; kk += 32) {
          const int go = ((((kk >> 3) + hi) << 3) ^ aswz);
          const short8 xla = *reinterpret_cast<const short8*>(aLA + go);
          const short8 xls = *reinterpret_cast<const short8*>(aLS + go);
          const short8 xx  = *reinterpret_cast<const short8*>(aX + go);
          const short8 xp  = *reinterpret_cast<const short8*>(aP + go);
          h0  = __builtin_amdgcn_mfma_f32_16x16x32_bf16(xla, *reinterpret_cast<const short8*>(wo1 + kk),        h0, 0,0,0);
          h1  = __builtin_amdgcn_mfma_f32_16x16x32_bf16(xls, *reinterpret_cast<const short8*>(wo1 + 512 + kk),  h1, 0,0,0);
          h2  = __builtin_amdgcn_mfma_f32_16x16x32_bf16(xp,  *reinterpret_cast<const short8*>(wo1 + 1024 + kk), h2, 0,0,0);
          na0 = __builtin_amdgcn_mfma_f32_16x16x32_bf16(xla, *reinterpret_cast<const short8*>(was + kk),        na0, 0,0,0);
          na1 = __builtin_amdgcn_mfma_f32_16x16x32_bf16(xx,  *reinterpret_cast<const short8*>(was + 512 + kk),  na1, 0,0,0);
          ns0 = __builtin_amdgcn_mfma_f32_16x16x32_bf16(xls, *reinterpret_cast<const short8*>(wss + kk),        ns0, 0,0,0);
          ns1 = __builtin_amdgcn_mfma_f32_16x16x32_bf16(xx,  *reinterpret_cast<const short8*>(wss + 512 + kk),  ns1, 0,0,0);
        }
      }

      float pv[4];
#pragma unroll
      for (int q = 0; q < 4; ++q) {
        const float h = fmaxf(h0[q] + h1[q] + h2[q] + bo1, 0.f);
        pv[q] = h * wo2;
      }
#pragma unroll
      for (int msk = 1; msk < 16; msk <<= 1) {
#pragma unroll
        for (int q = 0; q < 4; ++q) pv[q] += __shfl_xor(pv[q], msk, 64);
      }
      if (cc == 0) {
#pragma unroll
        for (int q = 0; q < 4; ++q) atomicAdd(&P_lds[r0 + q], pv[q]);
      }

      uint_t qa[4], qs[4];
#pragma unroll
      for (int q = 0; q < 4; ++q) {
        float x = na0[q] + na1[q] + bas;
        x = fminf(fmaxf(x, -12.f), 12.f);
        float e = __expf(2.f * x);
        const float nav = la[gg][q] + (e - 1.f) / (e + 1.f);
        as[gg][q] = nav;
        qa[q] = f2bf(nav);

        float y = ns0[q] + ns1[q] + bss;
        y = fminf(fmaxf(y, -12.f), 12.f);
        e = __expf(2.f * y);
        const float nsv = ls[gg][q] + (e - 1.f) / (e + 1.f);
        qs[q] = f2bf(nsv);
      }
#pragma unroll
      for (int q = 0; q < 4; ++q) {
        const uint_t va = qa[q] | (((uint_t)__shfl_xor((int)qa[q], 1, 64)) << 16);
        const uint_t vs = qs[q] | (((uint_t)__shfl_xor((int)qs[q], 1, 64)) << 16);
        const ull_t wa = (ull_t)va | ((ull_t)(uint_t)__shfl_xor((int)va, 2, 64) << 32);
        const ull_t wv = (ull_t)vs | ((ull_t)(uint_t)__shfl_xor((int)vs, 2, 64) << 32);
        if ((cc & 3) == 0) {
          const size_t row = (size_t)(bset + goff + r0 + q);
          coh_st8(ASG + row * 512 + ncol, wa);
          coh_st8(SKB + (row * 199 + (size_t)s) * 512 + ncol, wv);
        }
      }
      bar_signal(Cd[gg]);
      if (tid < 32)
        atomicAdd(&d_out[(size_t)(bset + goff + tid) * 199 + s], P_lds[tid]);
    }
  }
}

// ---------------- tail: out = sigmoid(out + b_o2) ----------------
__global__ void rekt_out(float* __restrict__ d_out, const float* __restrict__ b_o2) {
  const int i = blockIdx.x * blockDim.x + threadIdx.x;
  if (i < 512 * 199) {
    const float v = d_out[i] + b_o2[0];
    d_out[i] = 1.f / (1.f + __expf(-v));
  }
}

extern "C" void kernel_launch(void* const* d_in, const int* in_sizes, int n_in,
                              void* d_out, int out_size, void* d_ws, size_t ws_size,
                              hipStream_t stream) {
  const int*   next_skill   = (const int*)d_in[4];
  const int*   next_ans     = (const int*)d_in[5];
  const float* skill_embed  = (const float*)d_in[6];
  const float* ans_embed    = (const float*)d_in[7];
  const float* time_embed   = (const float*)d_in[8];
  const float* ls_state     = (const float*)d_in[9];
  const float* skill_state0 = (const float*)d_in[10];
  const float* W_sf = (const float*)d_in[11];
  const float* b_sf = (const float*)d_in[12];
  const float* W_af = (const float*)d_in[13];
  const float* b_af = (const float*)d_in[14];
  const float* W_ss = (const float*)d_in[15];
  const float* b_ss = (const float*)d_in[16];
  const float* W_as = (const float*)d_in[17];
  const float* b_as = (const float*)d_in[18];
  const float* W_o1 = (const float*)d_in[19];
  const float* b_o1 = (const float*)d_in[20];
  const float* W_o2 = (const float*)d_in[21];
  const float* b_o2 = (const float*)d_in[22];
  float* out = (float*)d_out;
  char*  ws  = (char*)d_ws;

  if (ws_size < WS_NEED) return;

  rekt_prep<<<dim3(1024), dim3(256), 0, stream>>>(
      skill_embed, ans_embed, ls_state, skill_state0,
      W_sf, W_af, W_ss, W_as, W_o1, out, ws);
  rekt_gap<<<dim3(201), dim3(512), 0, stream>>>(time_embed, W_sf, b_sf, W_af, b_af, ws);

  rekt_main<<<dim3(64), dim3(512), 0, stream>>>(
      next_skill, next_ans, ls_state, b_o1, W_o2, b_as, b_ss, out, ws);

  rekt_out<<<dim3((512 * 199 + 255) / 256), dim3(256), 0, stream>>>(out, b_o2);
}

// Round 7
// 5113.963 us; speedup vs baseline: 4.2062x; 4.2062x over previous
//
#include <hip/hip_runtime.h>

typedef unsigned short ushort_t;
typedef unsigned int uint_t;
typedef unsigned long long ull_t;
typedef __attribute__((ext_vector_type(8))) short short8;
typedef __attribute__((ext_vector_type(4))) float f32x4;

// ---------------- workspace layout (bytes) ----------------
constexpr size_t OFF_WSFT  = 0;                          // bf16 [512][512] (n,k): W_sf[k][n], k<512
constexpr size_t OFF_WAFT  = OFF_WSFT  + 512*512*2;      // bf16 [512][512]
constexpr size_t OFF_WO1AT = OFF_WAFT  + 512*512*2;      // bf16 [512][512]  W_o1 rows 0..511
constexpr size_t OFF_WO1BT = OFF_WO1AT + 512*512*2;      // bf16 [512][512]  W_o1 rows 512..1023
constexpr size_t OFF_WAST  = OFF_WO1BT + 512*512*2;      // bf16 [512][512]  W_as top
constexpr size_t OFF_WSST  = OFF_WAST  + 512*512*2;      // bf16 [512][512]  W_ss top
constexpr size_t OFF_GAPS  = OFF_WSST  + 512*512*2;      // f32 [200][512]  te@Wsf_bot + b_sf
constexpr size_t OFF_CAFV  = OFF_GAPS  + 200*512*4;      // f32 [512]       te1@Waf_bot + b_af
constexpr size_t OFF_XA    = OFF_CAFV  + 512*4;          // f32 [600][512]  X@Was_bot + b_as
constexpr size_t OFF_XS    = OFF_XA    + 600*512*4;      // f32 [600][512]  X@Wss_bot + b_ss
constexpr size_t OFF_PROJ  = OFF_XS    + 600*512*4;      // f32 [300][512]  se@Wo1c + b_o1
constexpr size_t OFF_LAG   = OFF_PROJ  + 300*512*4;      // bf16 [512][512] gated last_all
constexpr size_t OFF_LSG   = OFF_LAG   + 512*512*2;      // bf16 [512][512] gated last_sk
constexpr size_t OFF_ASG   = OFF_LSG   + 512*512*2;      // bf16 [512][512] all_state
constexpr size_t OFF_BAR   = OFF_ASG   + 512*512*2;      // i32 [16][32] barrier counters
constexpr size_t OFF_SKB   = OFF_BAR   + 16*32*4;        // bf16 [512][199][512] skill_buf
constexpr size_t WS_NEED   = OFF_SKB   + (size_t)512*199*512*2;

__device__ __forceinline__ ushort_t f2bf(float f) {
  union { float f; uint_t u; } v; v.f = f;
  uint_t u = v.u;
  return (ushort_t)((u + 0x7FFFu + ((u >> 16) & 1u)) >> 16);
}
__device__ __forceinline__ float bf2f(ushort_t h) {
  union { uint_t u; float f; } v; v.u = ((uint_t)h) << 16;
  return v.f;
}
__device__ __forceinline__ ull_t coh_ld8(const void* p) {
  return __hip_atomic_load((const ull_t*)p, __ATOMIC_RELAXED, __HIP_MEMORY_SCOPE_AGENT);
}
__device__ __forceinline__ void coh_st4(void* p, uint_t v) {
  __hip_atomic_store((uint_t*)p, v, __ATOMIC_RELAXED, __HIP_MEMORY_SCOPE_AGENT);
}

// ---------------- prologue: transposes + state init ----------------
__global__ void rekt_prep(const float* __restrict__ ls_state, const float* __restrict__ skill_state0,
                          const float* __restrict__ W_sf, const float* __restrict__ W_af,
                          const float* __restrict__ W_ss, const float* __restrict__ W_as,
                          const float* __restrict__ W_o1,
                          float* __restrict__ d_out, char* __restrict__ ws) {
  ushort_t* WSFT  = (ushort_t*)(ws + OFF_WSFT);
  ushort_t* WAFT  = (ushort_t*)(ws + OFF_WAFT);
  ushort_t* WO1AT = (ushort_t*)(ws + OFF_WO1AT);
  ushort_t* WO1BT = (ushort_t*)(ws + OFF_WO1BT);
  ushort_t* WAST  = (ushort_t*)(ws + OFF_WAST);
  ushort_t* WSST  = (ushort_t*)(ws + OFF_WSST);
  ushort_t* ASG   = (ushort_t*)(ws + OFF_ASG);
  int*      BARp  = (int*)(ws + OFF_BAR);
  ushort_t* SKB   = (ushort_t*)(ws + OFF_SKB);

  const size_t t0 = (size_t)blockIdx.x * blockDim.x + threadIdx.x;
  const size_t st = (size_t)gridDim.x * blockDim.x;

  for (size_t i = t0; i < 512*512; i += st) {
    const int k = (int)(i >> 9), n = (int)(i & 511);
    const size_t d = (size_t)n * 512 + k;
    WSFT[d]  = f2bf(W_sf[i]);
    WAFT[d]  = f2bf(W_af[i]);
    WAST[d]  = f2bf(W_as[i]);
    WSST[d]  = f2bf(W_ss[i]);
    WO1AT[d] = f2bf(W_o1[i]);
    WO1BT[d] = f2bf(W_o1[i + (size_t)512*512]);
  }
  for (size_t i = t0; i < 512*512; i += st) ASG[i] = f2bf(ls_state[i & 511]);
  for (size_t i = t0; i < 512*512; i += st) {
    const size_t b = i >> 9, n = i & 511;
    SKB[(b * 199) * 512 + n] = f2bf(skill_state0[n]);
  }
  for (size_t i = t0; i < 512*199; i += st) d_out[i] = 0.f;
  for (size_t i = t0; i < 16*32; i += st) BARp[i] = 0;
}

// ---------------- tables: XA/XS/PROJ/GAPS/CAF ----------------
__global__ void rekt_tab(const float* __restrict__ se, const float* __restrict__ ae,
                         const float* __restrict__ te,
                         const float* __restrict__ W_sf, const float* __restrict__ b_sf,
                         const float* __restrict__ W_af, const float* __restrict__ b_af,
                         const float* __restrict__ W_ss, const float* __restrict__ b_ss,
                         const float* __restrict__ W_as, const float* __restrict__ b_as,
                         const float* __restrict__ W_o1, const float* __restrict__ b_o1,
                         char* __restrict__ ws) {
  __shared__ float ar[512];
  const int n = threadIdx.x;
  const int bid = blockIdx.x;
  const float* W; const float* bias; float* dst;
  if (bid < 600) {
    const int a = bid / 300, sk = bid % 300;
    ar[n] = se[(size_t)sk*512 + n] + ae[(size_t)a*512 + n];
    W = W_as + (size_t)512*512; bias = b_as; dst = (float*)(ws + OFF_XA) + (size_t)bid*512;
  } else if (bid < 1200) {
    const int r = bid - 600, a = r / 300, sk = r % 300;
    ar[n] = se[(size_t)sk*512 + n] + ae[(size_t)a*512 + n];
    W = W_ss + (size_t)512*512; bias = b_ss; dst = (float*)(ws + OFF_XS) + (size_t)r*512;
  } else if (bid < 1500) {
    const int r = bid - 1200;
    ar[n] = se[(size_t)r*512 + n];
    W = W_o1 + (size_t)1024*512; bias = b_o1; dst = (float*)(ws + OFF_PROJ) + (size_t)r*512;
  } else if (bid < 1700) {
    const int t = bid - 1500;
    ar[n] = te[(size_t)t*512 + n];
    W = W_sf + (size_t)512*512; bias = b_sf; dst = (float*)(ws + OFF_GAPS) + (size_t)t*512;
  } else {
    ar[n] = te[512 + n];
    W = W_af + (size_t)512*512; bias = b_af; dst = (float*)(ws + OFF_CAFV);
  }
  __syncthreads();
  float acc = bias[n];
  for (int k = 0; k < 512; ++k) acc = fmaf(ar[k], W[(size_t)k*512 + n], acc);
  dst[n] = acc;
}

// ---------------- fence-free split barrier (16 blocks/group), bounded spin ----------------
__device__ __forceinline__ void bar_sig(int* c) {
  __syncthreads();                    // drains vm stores before the signal
  if (threadIdx.x == 0)
    __hip_atomic_fetch_add(c, 1, __ATOMIC_RELAXED, __HIP_MEMORY_SCOPE_AGENT);
}
__device__ __forceinline__ void bar_wait(int* c, int target) {
  if (threadIdx.x == 0) {
    int guard = 0;
    while (__hip_atomic_load(c, __ATOMIC_RELAXED, __HIP_MEMORY_SCOPE_AGENT) < target) {
      __builtin_amdgcn_s_sleep(1);
      if (++guard > (1 << 22)) break;  // fail loud (bad absmax), never hang
    }
  }
  __syncthreads();
}

// ---------------- staging: 32 rows x 512 bf16 -> swizzled LDS tile (coherent 8B loads) ----------------
__device__ __forceinline__ void stage_g(short* T, const ushort_t* __restrict__ base,
                                        const int* rows, int tid) {
#pragma unroll
  for (int t = 0; t < 8; ++t) {
    const int i = t * 512 + tid;
    const int r = i >> 7, u = i & 127;
    const ull_t v = coh_ld8((const ull_t*)(base + (size_t)rows[r] * 512) + u);
    *reinterpret_cast<ull_t*>(T + r * 512 + ((((u >> 1) ^ (r & 7)) << 3) | ((u & 1) << 2))) = v;
  }
}
__device__ __forceinline__ void stage_l(short* T, const ushort_t* __restrict__ base, int tid) {
#pragma unroll
  for (int t = 0; t < 8; ++t) {
    const int i = t * 512 + tid;
    const int r = i >> 7, u = i & 127;
    const ull_t v = coh_ld8((const ull_t*)(base + (size_t)r * 512) + u);
    *reinterpret_cast<ull_t*>(T + r * 512 + ((((u >> 1) ^ (r & 7)) << 3) | ((u & 1) << 2))) = v;
  }
}

#define MFMA(a, b, c) __builtin_amdgcn_mfma_f32_16x16x32_bf16((a), (b), (c), 0, 0, 0)

// ---------------- main scan ----------------
// 256 blocks = 16 groups (32 batches) x 16 N-slices (32 cols).  512 thr = 8 waves:
// wave w: m = w&1 (16 rows), nt = (w>>1)&1 (16 cols), set = w>>2 (0:{fa,ha,na} 1:{ga,hb,ns}).
__global__ __launch_bounds__(512, 2) void rekt_main(
    const int* __restrict__ next_skill, const int* __restrict__ next_ans,
    const float* __restrict__ w_o2,
    float* __restrict__ d_out, char* __restrict__ ws) {

  const ushort_t* WSFT  = (const ushort_t*)(ws + OFF_WSFT);
  const ushort_t* WAFT  = (const ushort_t*)(ws + OFF_WAFT);
  const ushort_t* WO1AT = (const ushort_t*)(ws + OFF_WO1AT);
  const ushort_t* WO1BT = (const ushort_t*)(ws + OFF_WO1BT);
  const ushort_t* WAST  = (const ushort_t*)(ws + OFF_WAST);
  const ushort_t* WSST  = (const ushort_t*)(ws + OFF_WSST);
  const float* GAPS = (const float*)(ws + OFF_GAPS);
  const float* CAFV = (const float*)(ws + OFF_CAFV);
  const float* XA   = (const float*)(ws + OFF_XA);
  const float* XS   = (const float*)(ws + OFF_XS);
  const float* PROJ = (const float*)(ws + OFF_PROJ);
  ushort_t* LAG = (ushort_t*)(ws + OFF_LAG);
  ushort_t* LSG = (ushort_t*)(ws + OFF_LSG);
  ushort_t* ASG = (ushort_t*)(ws + OFF_ASG);
  int*      BARp = (int*)(ws + OFF_BAR);
  ushort_t* SKB = (ushort_t*)(ws + OFF_SKB);

  __shared__ __align__(16) short Ta[32 * 512];
  __shared__ __align__(16) short Tb[32 * 512];
  __shared__ float Hbuf[32 * 32];
  __shared__ unsigned char LT[32 * 300];
  __shared__ int sk_s[32], gap_s[32], xr_s[32], skrow_s[32];

  const int tid = threadIdx.x;
  const int lane = tid & 63, w = tid >> 6;
  const int cc = lane & 15, hi = lane >> 4;
  const int m = w & 1, nt = (w >> 1) & 1, setB = w >> 2;
  const int g = blockIdx.x >> 4, sl = blockIdx.x & 15;
  const int b0 = g << 5;
  const int nc = sl * 32 + nt * 16 + cc;       // this lane's output column
  const int ncl = nt * 16 + cc;                // block-local column
  const int arow = m * 16 + cc;                // A-fragment row in tile
  const int r0 = m * 16 + hi * 4;              // acc row base
  const int aswz = (cc & 7) << 3;
  int* cA = BARp + g * 32;
  int* cB = cA + 1;

  const float cafv = CAFV[nc];
  const float wo2v = w_o2[nc];

  // this wave's B-operand column pointers ([n][k] layout, frag at col nc, k = kk*32 + hi*8)
  const ushort_t* BA = (setB ? WAFT  : WSFT ) + (size_t)nc * 512 + hi * 8;
  const ushort_t* BH = (setB ? WO1BT : WO1AT) + (size_t)nc * 512 + hi * 8;
  const ushort_t* BU = (setB ? WSST  : WAST ) + (size_t)nc * 512 + hi * 8;

  for (int i = tid; i < 32 * 300; i += 512) LT[i] = 0;
  __syncthreads();

  for (int s = 0; s < 199; ++s) {
    bar_wait(cB, 16 * s);                      // prev step's AS/SKB visible (L3)

    if (tid < 32) {
      const int b = b0 + tid;
      const int sk = next_skill[b * 199 + s];
      const int tl = (int)LT[tid * 300 + sk];
      sk_s[tid] = sk;
      gap_s[tid] = s - tl;
      xr_s[tid] = next_ans[b * 199 + s] * 300 + sk;
      skrow_s[tid] = b * 199 + tl;
      LT[tid * 300 + sk] = (unsigned char)s;
    }
    __syncthreads();

    // ---- stage: Ta = SKg (gather), Tb = AS ----
    stage_g(Ta, SKB, skrow_s, tid);
    stage_l(Tb, ASG + (size_t)b0 * 512, tid);
    __syncthreads();

    // ---- phase A: set0 fa = SKg@Wsf ; set1 ga = AS@Waf (B prefetched to regs) ----
    f32x4 accA = {0.f, 0.f, 0.f, 0.f};
    {
      const short* a0 = (setB ? Tb : Ta) + arow * 512;
      short8 Bf[16];
#pragma unroll
      for (int j = 0; j < 16; ++j) Bf[j] = *reinterpret_cast<const short8*>(BA + j * 32);
#pragma unroll
      for (int j = 0; j < 16; ++j) {
        const short8 a = *reinterpret_cast<const short8*>(a0 + (((j * 4 + hi) << 3) ^ aswz));
        accA = MFMA(a, Bf[j], accA);
      }
    }

    // ---- epilogue A ----
    if (setB == 0) {                            // LS = SKg * sigmoid(fa + GAPS[gap])
#pragma unroll
      for (int q = 0; q < 4; ++q) {
        const int r = r0 + q;
        const float F = accA[q] + GAPS[(size_t)gap_s[r] * 512 + nc];
        const float sg = 1.f / (1.f + __expf(-F));
        const float skg = bf2f((ushort_t)Ta[r * 512 + (((nc >> 3) ^ (r & 7)) << 3) + (nc & 7)]);
        const uint_t pz = f2bf(skg * sg);
        const uint_t oz = (uint_t)__shfl_xor((int)pz, 1, 64);
        if (!(cc & 1)) coh_st4(LSG + (size_t)(b0 + r) * 512 + nc, pz | (oz << 16));
      }
    } else {                                    // LA = AS * sigmoid(ga + CAF)
#pragma unroll
      for (int q = 0; q < 4; ++q) {
        const int r = r0 + q;
        const float G = accA[q] + cafv;
        const float sg = 1.f / (1.f + __expf(-G));
        const float asv = bf2f((ushort_t)Tb[r * 512 + (((nc >> 3) ^ (r & 7)) << 3) + (nc & 7)]);
        const uint_t pz = f2bf(asv * sg);
        const uint_t oz = (uint_t)__shfl_xor((int)pz, 1, 64);
        if (!(cc & 1)) coh_st4(LAG + (size_t)(b0 + r) * 512 + nc, pz | (oz << 16));
      }
    }
    bar_sig(cA);
    bar_wait(cA, 16 * (s + 1));                 // all slices' LA/LS visible

    // ---- stage: Ta = LA, Tb = LS ----
    stage_l(Ta, LAG + (size_t)b0 * 512, tid);
    stage_l(Tb, LSG + (size_t)b0 * 512, tid);
    __syncthreads();

    // ---- phase B: set0 {ha, na} from LA ; set1 {hb, ns} from LS ----
    f32x4 acc1 = {0.f, 0.f, 0.f, 0.f}, acc2 = {0.f, 0.f, 0.f, 0.f};
    {
      const short* a0 = (setB ? Tb : Ta) + arow * 512;
      short8 B1[16], B2[16];
#pragma unroll
      for (int j = 0; j < 16; ++j) {
        B1[j] = *reinterpret_cast<const short8*>(BH + j * 32);
        B2[j] = *reinterpret_cast<const short8*>(BU + j * 32);
      }
#pragma unroll
      for (int j = 0; j < 16; ++j) {
        const short8 a = *reinterpret_cast<const short8*>(a0 + (((j * 4 + hi) << 3) ^ aswz));
        acc1 = MFMA(a, B1[j], acc1);
        acc2 = MFMA(a, B2[j], acc2);
      }
    }

    // ---- epilogue B ----
    if (setB == 0) {                            // publish ha partial
#pragma unroll
      for (int q = 0; q < 4; ++q) Hbuf[(r0 + q) * 32 + ncl] = acc1[q];
    }
    __syncthreads();

    if (setB == 0) {                            // AS' = LA + tanh(na + XA[xr])
#pragma unroll
      for (int q = 0; q < 4; ++q) {
        const int r = r0 + q;
        float x = acc2[q] + XA[(size_t)xr_s[r] * 512 + nc];
        x = fminf(fmaxf(x, -12.f), 12.f);
        const float e = __expf(2.f * x);
        const float lav = bf2f((ushort_t)Ta[r * 512 + (((nc >> 3) ^ (r & 7)) << 3) + (nc & 7)]);
        const uint_t pz = f2bf(lav + (e - 1.f) / (e + 1.f));
        const uint_t oz = (uint_t)__shfl_xor((int)pz, 1, 64);
        if (!(cc & 1)) coh_st4(ASG + (size_t)(b0 + r) * 512 + nc, pz | (oz << 16));
      }
    } else {                                    // P partial + SK' = LS + tanh(ns + XS[xr])
      float pv[4];
#pragma unroll
      for (int q = 0; q < 4; ++q) {
        const int r = r0 + q;
        const float h = fmaxf(Hbuf[r * 32 + ncl] + acc1[q] + PROJ[(size_t)sk_s[r] * 512 + nc], 0.f);
        pv[q] = h * wo2v;

        float y = acc2[q] + XS[(size_t)xr_s[r] * 512 + nc];
        y = fminf(fmaxf(y, -12.f), 12.f);
        const float e = __expf(2.f * y);
        const float lsv = bf2f((ushort_t)Tb[r * 512 + (((nc >> 3) ^ (r & 7)) << 3) + (nc & 7)]);
        const uint_t pz = f2bf(lsv + (e - 1.f) / (e + 1.f));
        const uint_t oz = (uint_t)__shfl_xor((int)pz, 1, 64);
        if (!(cc & 1)) coh_st4(SKB + ((size_t)(b0 + r) * 199 + s) * 512 + nc, pz | (oz << 16));
      }
#pragma unroll
      for (int msk = 1; msk < 16; msk <<= 1) {
#pragma unroll
        for (int q = 0; q < 4; ++q) pv[q] += __shfl_xor(pv[q], msk, 64);
      }
      if (cc == 0) {
#pragma unroll
        for (int q = 0; q < 4; ++q) atomicAdd(&d_out[(size_t)(b0 + r0 + q) * 199 + s], pv[q]);
      }
    }
    bar_sig(cB);
  }
}

// ---------------- tail: out = sigmoid(out + b_o2) ----------------
__global__ void rekt_out(float* __restrict__ d_out, const float* __restrict__ b_o2) {
  const int i = blockIdx.x * blockDim.x + threadIdx.x;
  if (i < 512 * 199) {
    const float v = d_out[i] + b_o2[0];
    d_out[i] = 1.f / (1.f + __expf(-v));
  }
}

extern "C" void kernel_launch(void* const* d_in, const int* in_sizes, int n_in,
                              void* d_out, int out_size, void* d_ws, size_t ws_size,
                              hipStream_t stream) {
  const int*   next_skill   = (const int*)d_in[4];
  const int*   next_ans     = (const int*)d_in[5];
  const float* skill_embed  = (const float*)d_in[6];
  const float* ans_embed    = (const float*)d_in[7];
  const float* time_embed   = (const float*)d_in[8];
  const float* ls_state     = (const float*)d_in[9];
  const float* skill_state0 = (const float*)d_in[10];
  const float* W_sf = (const float*)d_in[11];
  const float* b_sf = (const float*)d_in[12];
  const float* W_af = (const float*)d_in[13];
  const float* b_af = (const float*)d_in[14];
  const float* W_ss = (const float*)d_in[15];
  const float* b_ss = (const float*)d_in[16];
  const float* W_as = (const float*)d_in[17];
  const float* b_as = (const float*)d_in[18];
  const float* W_o1 = (const float*)d_in[19];
  const float* b_o1 = (const float*)d_in[20];
  const float* W_o2 = (const float*)d_in[21];
  const float* b_o2 = (const float*)d_in[22];
  float* out = (float*)d_out;
  char*  ws  = (char*)d_ws;

  if (ws_size < WS_NEED) return;

  rekt_prep<<<dim3(2048), dim3(256), 0, stream>>>(
      ls_state, skill_state0, W_sf, W_af, W_ss, W_as, W_o1, out, ws);
  rekt_tab<<<dim3(1701), dim3(512), 0, stream>>>(
      skill_embed, ans_embed, time_embed,
      W_sf, b_sf, W_af, b_af, W_ss, b_ss, W_as, b_as, W_o1, b_o1, ws);

  rekt_main<<<dim3(256), dim3(512), 0, stream>>>(
      next_skill, next_ans, W_o2, out, ws);

  rekt_out<<<dim3((512 * 199 + 255) / 256), dim3(256), 0, stream>>>(out, b_o2);
}